// Round 11
// baseline (161.402 us; speedup 1.0000x reference)
//
#include <hip/hip_runtime.h>

#define USER_COUNT 100000
#define ITEM_COUNT 50000
#define N_NODES    150000   // USER_COUNT + ITEM_COUNT
#define EMB        64
#define N_EDGES    1250000
#define BATCH      4096

#define BROWS     512                 // rows per bucket
#define NBKT      293                 // ceil(150000 / 512), bucket = row >> 9
#define A1_TILE   2048
#define A1_BLOCKS ((N_EDGES + A1_TILE - 1) / A1_TILE)   // 611
#define PSTR      320                 // partT row stride (ints), >= NBKT
#define COLMASK   0x3FFFFu
#define ROW_ALLOC 150536              // >= NBKT*BROWS (150016) + 1, padded
#define NLIST_PAD 150016
#define BITWORDS  4704                // ceil(150000/32)=4688, padded
#define CSR_CAP   5120                // LDS staging capacity (avg bucket ~4267)

#define CONCAT_BLOCKS 9375            // N_NODES*EMB/4 / 256

// bf16x2 pack/unpack (round-to-nearest-even; inputs are finite)
static __device__ __forceinline__ unsigned pack_bf16x2(float a, float b) {
    unsigned ua = __float_as_uint(a);
    unsigned ub = __float_as_uint(b);
    ua += 0x7FFFu + ((ua >> 16) & 1u);
    ub += 0x7FFFu + ((ub >> 16) & 1u);
    return (ua >> 16) | (ub & 0xFFFF0000u);
}
static __device__ __forceinline__ float2 unpack_bf16x2(unsigned v) {
    float2 r;
    r.x = __uint_as_float(v << 16);
    r.y = __uint_as_float(v & 0xFFFF0000u);
    return r;
}

static __device__ __forceinline__ const float* ego_ptr(unsigned c,
                                                       const float* __restrict__ ue,
                                                       const float* __restrict__ ie) {
    return (c < USER_COUNT) ? ue + (size_t)c * EMB
                            : ie + (size_t)(c - USER_COUNT) * EMB;
}

// ---------------------------------------------------------------------------
// 32-lane-group SpMM row body, unroll 8/4/1 (avg degree 8.33): up to 8 row
// gathers in flight per group. Lane owns dims (2l, 2l+1).
// ---------------------------------------------------------------------------
static __device__ __forceinline__ float2 spmm_row(const uint2* __restrict__ edges,
                                                  int s, int e,
                                                  const unsigned* __restrict__ xin,
                                                  int l) {
    float ax0 = 0.f, ay0 = 0.f, ax1 = 0.f, ay1 = 0.f;
    float ax2 = 0.f, ay2 = 0.f, ax3 = 0.f, ay3 = 0.f;
    int i = s;
    for (; i + 7 < e; i += 8) {
        uint2 e0 = edges[i];
        uint2 e1 = edges[i + 1];
        uint2 e2 = edges[i + 2];
        uint2 e3 = edges[i + 3];
        uint2 e4 = edges[i + 4];
        uint2 e5 = edges[i + 5];
        uint2 e6 = edges[i + 6];
        uint2 e7 = edges[i + 7];
        float2 v0 = unpack_bf16x2(xin[(size_t)(e0.x & COLMASK) * 32 + l]);
        float2 v1 = unpack_bf16x2(xin[(size_t)(e1.x & COLMASK) * 32 + l]);
        float2 v2 = unpack_bf16x2(xin[(size_t)(e2.x & COLMASK) * 32 + l]);
        float2 v3 = unpack_bf16x2(xin[(size_t)(e3.x & COLMASK) * 32 + l]);
        float2 v4 = unpack_bf16x2(xin[(size_t)(e4.x & COLMASK) * 32 + l]);
        float2 v5 = unpack_bf16x2(xin[(size_t)(e5.x & COLMASK) * 32 + l]);
        float2 v6 = unpack_bf16x2(xin[(size_t)(e6.x & COLMASK) * 32 + l]);
        float2 v7 = unpack_bf16x2(xin[(size_t)(e7.x & COLMASK) * 32 + l]);
        float w0 = __uint_as_float(e0.y), w1 = __uint_as_float(e1.y);
        float w2 = __uint_as_float(e2.y), w3 = __uint_as_float(e3.y);
        float w4 = __uint_as_float(e4.y), w5 = __uint_as_float(e5.y);
        float w6 = __uint_as_float(e6.y), w7 = __uint_as_float(e7.y);
        ax0 += w0 * v0.x; ay0 += w0 * v0.y;
        ax1 += w1 * v1.x; ay1 += w1 * v1.y;
        ax2 += w2 * v2.x; ay2 += w2 * v2.y;
        ax3 += w3 * v3.x; ay3 += w3 * v3.y;
        ax0 += w4 * v4.x; ay0 += w4 * v4.y;
        ax1 += w5 * v5.x; ay1 += w5 * v5.y;
        ax2 += w6 * v6.x; ay2 += w6 * v6.y;
        ax3 += w7 * v7.x; ay3 += w7 * v7.y;
    }
    if (i + 3 < e) {
        uint2 e0 = edges[i];
        uint2 e1 = edges[i + 1];
        uint2 e2 = edges[i + 2];
        uint2 e3 = edges[i + 3];
        float w0 = __uint_as_float(e0.y), w1 = __uint_as_float(e1.y);
        float w2 = __uint_as_float(e2.y), w3 = __uint_as_float(e3.y);
        float2 v0 = unpack_bf16x2(xin[(size_t)(e0.x & COLMASK) * 32 + l]);
        float2 v1 = unpack_bf16x2(xin[(size_t)(e1.x & COLMASK) * 32 + l]);
        float2 v2 = unpack_bf16x2(xin[(size_t)(e2.x & COLMASK) * 32 + l]);
        float2 v3 = unpack_bf16x2(xin[(size_t)(e3.x & COLMASK) * 32 + l]);
        ax0 += w0 * v0.x; ay0 += w0 * v0.y;
        ax1 += w1 * v1.x; ay1 += w1 * v1.y;
        ax2 += w2 * v2.x; ay2 += w2 * v2.y;
        ax3 += w3 * v3.x; ay3 += w3 * v3.y;
        i += 4;
    }
    for (; i < e; ++i) {
        uint2 e0 = edges[i];
        float w0 = __uint_as_float(e0.y);
        float2 v0 = unpack_bf16x2(xin[(size_t)(e0.x & COLMASK) * 32 + l]);
        ax0 += w0 * v0.x; ay0 += w0 * v0.y;
    }
    return make_float2((ax0 + ax1) + (ax2 + ax3), (ay0 + ay1) + (ay2 + ay3));
}

// ---------------------------------------------------------------------------
// Fused prep: blocks [0, CONCAT_BLOCKS) do ego->bf16 concat; blocks
// [CONCAT_BLOCKS, +A1_BLOCKS) do the per-block bucket histogram (no global
// atomics: block bb writes its 293 counts to partT[bb*PSTR+t]).
// ---------------------------------------------------------------------------
__global__ void k_prep(const float* __restrict__ ue, const float* __restrict__ ie,
                       unsigned* __restrict__ x,
                       const int* __restrict__ row, int* __restrict__ partT) {
    __shared__ int h[PSTR];
    int tid = threadIdx.x;
    if (blockIdx.x < CONCAT_BLOCKS) {
        const size_t nu4 = (size_t)USER_COUNT * EMB / 4;
        size_t i = (size_t)blockIdx.x * 256 + tid;
        float4 v = (i < nu4) ? ((const float4*)ue)[i] : ((const float4*)ie)[i - nu4];
        uint2 p;
        p.x = pack_bf16x2(v.x, v.y);
        p.y = pack_bf16x2(v.z, v.w);
        ((uint2*)x)[i] = p;
    } else {
        int bb = blockIdx.x - CONCAT_BLOCKS;
        h[tid] = 0;
        if (tid + 256 < PSTR) h[tid + 256] = 0;
        __syncthreads();
        int base = bb * A1_TILE;
        #pragma unroll
        for (int j = 0; j < 8; ++j) {
            int e = base + j * 256 + tid;
            if (e < N_EDGES) atomicAdd(&h[row[e] >> 9], 1);
        }
        __syncthreads();
        if (tid < NBKT) partT[bb * PSTR + tid] = h[tid];
        if (tid + 256 < NBKT) partT[bb * PSTR + tid + 256] = h[tid + 256];
    }
}

// ---------------------------------------------------------------------------
// Parallel column scan: block t exclusive-scans partT[:,t] (611 entries)
// in place and writes the column total to gtot[t].
// ---------------------------------------------------------------------------
__global__ void k_scanbkt(int* __restrict__ partT, int* __restrict__ gtot) {
    __shared__ int sA[256], sB[256];
    int t   = blockIdx.x;
    int tid = threadIdx.x;
    int v0 = 0, v1 = 0, v2 = 0;
    int b0 = tid * 3;
    if (b0 + 0 < A1_BLOCKS) v0 = partT[(b0 + 0) * PSTR + t];
    if (b0 + 1 < A1_BLOCKS) v1 = partT[(b0 + 1) * PSTR + t];
    if (b0 + 2 < A1_BLOCKS) v2 = partT[(b0 + 2) * PSTR + t];
    int s = v0 + v1 + v2;
    sA[tid] = s;
    __syncthreads();
    int* in = sA; int* out = sB;
    for (int off = 1; off < 256; off <<= 1) {
        out[tid] = in[tid] + ((tid >= off) ? in[tid - off] : 0);
        __syncthreads();
        int* tmp = in; in = out; out = tmp;
    }
    int run = in[tid] - s;
    if (b0 + 0 < A1_BLOCKS) { partT[(b0 + 0) * PSTR + t] = run; run += v0; }
    if (b0 + 1 < A1_BLOCKS) { partT[(b0 + 1) * PSTR + t] = run; run += v1; }
    if (b0 + 2 < A1_BLOCKS) { partT[(b0 + 2) * PSTR + t] = run; }
    if (tid == 255) gtot[t] = in[255];
}

// ---------------------------------------------------------------------------
// Cross-bucket scan: gtot[293] -> gstart (exclusive + sentinel), zero ncount.
// 2 elements per thread over 512 slots.
// ---------------------------------------------------------------------------
__global__ void k_scan2(const int* __restrict__ gtot,
                        int* __restrict__ gstart, int* __restrict__ ncount) {
    __shared__ int sA[512], sB[512];
    int tid = threadIdx.x;
    int va = (tid < NBKT) ? gtot[tid] : 0;
    int vb = (tid + 256 < NBKT) ? gtot[tid + 256] : 0;
    sA[tid] = va; sA[tid + 256] = vb;
    __syncthreads();
    int* in = sA; int* out = sB;
    for (int off = 1; off < 512; off <<= 1) {
        out[tid] = in[tid] + ((tid >= off) ? in[tid - off] : 0);
        int i2 = tid + 256;
        out[i2] = in[i2] + ((i2 >= off) ? in[i2 - off] : 0);
        __syncthreads();
        int* t = in; in = out; out = t;
    }
    if (tid <= NBKT)       gstart[tid] = in[tid] - va;
    if (tid + 256 <= NBKT) gstart[tid + 256] = in[tid + 256] - vb;
    if (tid == 255) ncount[0] = 0;
}

// ---------------------------------------------------------------------------
// Pass A1: bucket-sort edges into edges_a with coherent (staged) writes.
// Per-(block,bucket) base = gstart[t] + scanned partT[bb][t] — no atomics.
// Record: {col | (row&511)<<18, w_f32}
// ---------------------------------------------------------------------------
__global__ void k_binfill(const int* __restrict__ row, const int* __restrict__ col,
                          const float* __restrict__ w,
                          const int* __restrict__ partT,
                          const int* __restrict__ gstart,
                          uint2* __restrict__ edges_a) {
    __shared__ int cnt[512], cnt2[PSTR], gpos[PSTR], sc[PSTR];
    __shared__ int sA[512], sB[512];
    __shared__ uint2 srec[A1_TILE];
    __shared__ int  sdst[A1_TILE];
    int tid = threadIdx.x;
    cnt[tid] = 0; cnt[tid + 256] = 0;
    cnt2[tid] = 0;
    if (tid + 256 < PSTR) cnt2[tid + 256] = 0;
    __syncthreads();

    int ebase   = blockIdx.x * A1_TILE;
    int tilecnt = min(A1_TILE, N_EDGES - ebase);

    int r[8], c[8]; float wv[8];
    #pragma unroll
    for (int j = 0; j < 8; ++j) {
        int e = ebase + j * 256 + tid;
        if (e < N_EDGES) {
            r[j] = row[e]; c[j] = col[e]; wv[j] = w[e];
            atomicAdd(&cnt[r[j] >> 9], 1);
        } else {
            r[j] = -1;
        }
    }
    __syncthreads();

    // exclusive scan of cnt over 512 slots (2 per thread)
    int* in = sA; int* out = sB;
    in[tid] = cnt[tid]; in[tid + 256] = cnt[tid + 256];
    __syncthreads();
    for (int off = 1; off < 512; off <<= 1) {
        out[tid] = in[tid] + ((tid >= off) ? in[tid - off] : 0);
        int i2 = tid + 256;
        out[i2] = in[i2] + ((i2 >= off) ? in[i2 - off] : 0);
        __syncthreads();
        int* t = in; in = out; out = t;
    }
    #pragma unroll
    for (int k = 0; k < 2; ++k) {
        int b = tid + k * 256;
        if (b < NBKT) {
            sc[b]   = in[b] - cnt[b];
            gpos[b] = gstart[b] + partT[blockIdx.x * PSTR + b];
        }
    }
    __syncthreads();

    #pragma unroll
    for (int j = 0; j < 8; ++j) {
        if (r[j] >= 0) {
            int b  = r[j] >> 9;
            int lp = sc[b] + atomicAdd(&cnt2[b], 1);
            srec[lp] = make_uint2((unsigned)c[j] | ((unsigned)(r[j] & 511) << 18),
                                  __float_as_uint(wv[j]));
            sdst[lp] = gpos[b] + (lp - sc[b]);
        }
    }
    __syncthreads();

    #pragma unroll
    for (int j = 0; j < 8; ++j) {
        int i = j * 256 + tid;
        if (i < tilecnt) edges_a[sdst[i]] = srec[i];
    }
}

// ---------------------------------------------------------------------------
// Pass A2: per-bucket exact CSR, ONE global read pass (edges staged in LDS,
// CAP overflow falls back to global re-read). 293 blocks x 512 threads.
// ---------------------------------------------------------------------------
__global__ __launch_bounds__(512) void k_csrfill(const int* __restrict__ gstart,
                                                 const uint2* __restrict__ edges_a,
                                                 uint2* __restrict__ edges_b,
                                                 int* __restrict__ row_start) {
    __shared__ uint2 srec[CSR_CAP];               // 40 KB
    __shared__ int hist[512], cur[512];
    __shared__ int sA[512], sB[512];
    int tid   = threadIdx.x;
    int b     = blockIdx.x;
    int base  = gstart[b];
    int count = gstart[b + 1] - base;

    hist[tid] = 0;
    __syncthreads();
    for (int i = tid; i < count; i += 512) {
        uint2 rec = edges_a[base + i];
        if (i < CSR_CAP) srec[i] = rec;
        atomicAdd(&hist[(rec.x >> 18) & 511], 1);
    }
    __syncthreads();

    int hv = hist[tid];
    int* in = sA; int* out = sB;
    in[tid] = hv;
    __syncthreads();
    for (int off = 1; off < 512; off <<= 1) {
        out[tid] = in[tid] + ((tid >= off) ? in[tid - off] : 0);
        __syncthreads();
        int* t = in; in = out; out = t;
    }
    int excl = in[tid] - hv;
    row_start[b * BROWS + tid] = base + excl;
    cur[tid] = base + excl;
    __syncthreads();

    for (int i = tid; i < count; i += 512) {
        uint2 rec = (i < CSR_CAP) ? srec[i] : edges_a[base + i];
        int rl = (rec.x >> 18) & 511;
        int pos = atomicAdd(&cur[rl], 1);
        edges_b[pos] = rec;
    }
}

// ---------------------------------------------------------------------------
// Mark+append (dedup'd): bit-array atomicOr; first setter appends to nlist.
// ---------------------------------------------------------------------------
static __device__ __forceinline__ void bit_append(int n, unsigned* __restrict__ bits,
                                                  int* __restrict__ list,
                                                  int* __restrict__ count) {
    unsigned bit = 1u << (n & 31);
    unsigned old = atomicOr(&bits[n >> 5], bit);
    if (!(old & bit)) {
        int pos = atomicAdd(count, 1);
        list[pos] = n;
    }
}

__global__ void k_mark(const int* __restrict__ users, const int* __restrict__ items,
                       const int* __restrict__ row_start,
                       const uint2* __restrict__ edges_b,
                       unsigned* __restrict__ bits,
                       int* __restrict__ nlist, int* __restrict__ ncount) {
    int t = blockIdx.x * blockDim.x + threadIdx.x;
    int g = t >> 3;
    int l = t & 7;
    if (g >= 2 * BATCH) return;
    int node = (g < BATCH) ? users[g] : USER_COUNT + items[g - BATCH];
    if (l == 0) bit_append(node, bits, nlist, ncount);
    int s = row_start[node], e = row_start[node + 1];
    for (int i = s + l; i < e; i += 8)
        bit_append((int)(edges_b[i].x & COLMASK), bits, nlist, ncount);
}

// ---------------------------------------------------------------------------
// Full gather SpMM over bf16 table: 32-lane group per node
// ---------------------------------------------------------------------------
__global__ void k_spmm_bf16(const int* __restrict__ row_start,
                            const uint2* __restrict__ edges,
                            const unsigned* __restrict__ xin,
                            unsigned* __restrict__ xout) {
    int g = blockIdx.x * 8 + (threadIdx.x >> 5);
    int l = threadIdx.x & 31;
    if (g >= N_NODES) return;
    float2 a = spmm_row(edges, row_start[g], row_start[g + 1], xin, l);
    xout[(size_t)g * 32 + l] = pack_bf16x2(a.x, a.y);
}

// ---------------------------------------------------------------------------
// List-driven gather SpMM (layer 2 prune): only listed (unique) rows
// ---------------------------------------------------------------------------
__global__ void k_spmm_list(const int* __restrict__ row_start,
                            const uint2* __restrict__ edges,
                            const unsigned* __restrict__ xin,
                            unsigned* __restrict__ xout,
                            const int* __restrict__ list,
                            const int* __restrict__ count) {
    int gi = blockIdx.x * 8 + (threadIdx.x >> 5);
    if (gi >= *count) return;
    int g = list[gi];
    int l = threadIdx.x & 31;
    float2 a = spmm_row(edges, row_start[g], row_start[g + 1], xin, l);
    xout[(size_t)g * 32 + l] = pack_bf16x2(a.x, a.y);
}

// ---------------------------------------------------------------------------
// Fused epilogue: out[g] = 0.25*(ego + x1 + x2 + layer3(x2)), full write.
// ---------------------------------------------------------------------------
__global__ void k_epilogue(const int* __restrict__ users,
                           const int* __restrict__ items,
                           const float* __restrict__ ue,
                           const float* __restrict__ ie,
                           const unsigned* __restrict__ x1,
                           const unsigned* __restrict__ x2,
                           const int* __restrict__ row_start,
                           const uint2* __restrict__ edges,
                           float* __restrict__ out) {
    int g = blockIdx.x * 8 + (threadIdx.x >> 5);
    int l = threadIdx.x & 31;
    if (g >= 2 * BATCH) return;
    int node = (g < BATCH) ? users[g] : USER_COUNT + items[g - BATCH];
    float2 l3 = spmm_row(edges, row_start[node], row_start[node + 1], x2, l);
    float2 e = ((const float2*)ego_ptr((unsigned)node, ue, ie))[l];
    float2 a = unpack_bf16x2(x1[(size_t)node * 32 + l]);
    float2 b = unpack_bf16x2(x2[(size_t)node * 32 + l]);
    float2 r;
    r.x = 0.25f * (e.x + a.x + b.x + l3.x);
    r.y = 0.25f * (e.y + a.y + b.y + l3.y);
    ((float2*)out)[(size_t)g * 32 + l] = r;
}

extern "C" void kernel_launch(void* const* d_in, const int* in_sizes, int n_in,
                              void* d_out, int out_size, void* d_ws, size_t ws_size,
                              hipStream_t stream) {
    const float* user_emb    = (const float*)d_in[0];
    const float* item_emb    = (const float*)d_in[1];
    const int*   edge_row    = (const int*)d_in[2];
    const int*   edge_col    = (const int*)d_in[3];
    const float* edge_weight = (const float*)d_in[4];
    const int*   users       = (const int*)d_in[5];
    const int*   items       = (const int*)d_in[6];
    float* out = (float*)d_out;

    // ws layout (~80 MB)
    const size_t node_u32 = (size_t)N_NODES * 32;     // 19.2 MB per bf16 table
    unsigned* xa        = (unsigned*)d_ws;            // ego (bf16)
    unsigned* xb        = xa + node_u32;              // x1
    unsigned* xc        = xb + node_u32;              // x2 (pruned rows only)
    int*      row_start = (int*)(xc + node_u32);      // ROW_ALLOC ints
    int*      gstart    = row_start + ROW_ALLOC;      // 512
    int*      gtot      = gstart + 512;               // 512
    int*      partT     = gtot + 512;                 // A1_BLOCKS*PSTR = 195520
    unsigned* bits      = (unsigned*)(partT + A1_BLOCKS * PSTR);  // BITWORDS
    int*      ncount    = (int*)(bits + BITWORDS);    // 16
    int*      nlist     = ncount + 16;                // NLIST_PAD
    uint2*    edges_a   = (uint2*)(nlist + NLIST_PAD);   // 10 MB
    uint2*    edges_b   = edges_a + N_EDGES;             // 10 MB

    // single small memset: dedup bit-array + ncount (contiguous)
    hipMemsetAsync(bits, 0, (BITWORDS + 16) * sizeof(int), stream);

    // prep: concat->bf16 + per-block histogram (fused, no global atomics)
    k_prep<<<CONCAT_BLOCKS + A1_BLOCKS, 256, 0, stream>>>(user_emb, item_emb,
                                                          xa, edge_row, partT);

    // CSR build (atomic-free scans)
    k_scanbkt<<<NBKT, 256, 0, stream>>>(partT, gtot);
    k_scan2<<<1, 256, 0, stream>>>(gtot, gstart, ncount);
    k_binfill<<<A1_BLOCKS, 256, 0, stream>>>(edge_row, edge_col, edge_weight,
                                             partT, gstart, edges_a);
    k_csrfill<<<NBKT, 512, 0, stream>>>(gstart, edges_a, edges_b, row_start);

    // mark+append (dedup'd x2-needed rows)
    k_mark<<<(2 * BATCH * 8 + 255) / 256, 256, 0, stream>>>(users, items, row_start,
                                                            edges_b, bits,
                                                            nlist, ncount);

    // layers
    k_spmm_bf16<<<(N_NODES + 7) / 8, 256, 0, stream>>>(row_start, edges_b, xa, xb);
    k_spmm_list<<<(N_NODES + 7) / 8, 256, 0, stream>>>(row_start, edges_b, xb, xc,
                                                       nlist, ncount);

    // fused epilogue
    k_epilogue<<<(2 * BATCH + 7) / 8, 256, 0, stream>>>(users, items,
                                                        user_emb, item_emb,
                                                        xb, xc, row_start, edges_b,
                                                        out);
}

// Round 12
// 149.905 us; speedup vs baseline: 1.0767x; 1.0767x over previous
//
#include <hip/hip_runtime.h>

#define USER_COUNT 100000
#define ITEM_COUNT 50000
#define N_NODES    150000   // USER_COUNT + ITEM_COUNT
#define EMB        64
#define N_EDGES    1250000
#define BATCH      4096

#define BROWS     512                 // rows per bucket
#define NBKT      293                 // ceil(150000 / 512), bucket = row >> 9
#define A1_TILE   2048
#define A1_BLOCKS ((N_EDGES + A1_TILE - 1) / A1_TILE)   // 611
#define PSTR      320                 // partT row stride (ints), >= NBKT
#define COLMASK   0x3FFFFu
#define ROW_ALLOC 150536              // >= NBKT*BROWS (150016) + 1, padded
#define NLIST_PAD 150016
#define BITWORDS  4704                // ceil(150000/32)=4688, padded
#define CSR_CAP   5120                // LDS staging capacity (avg bucket ~4267)

#define CONCAT_BLOCKS 9375            // N_NODES*EMB/4 / 256

// bf16x2 pack/unpack (round-to-nearest-even; inputs are finite)
static __device__ __forceinline__ unsigned pack_bf16x2(float a, float b) {
    unsigned ua = __float_as_uint(a);
    unsigned ub = __float_as_uint(b);
    ua += 0x7FFFu + ((ua >> 16) & 1u);
    ub += 0x7FFFu + ((ub >> 16) & 1u);
    return (ua >> 16) | (ub & 0xFFFF0000u);
}

static __device__ __forceinline__ const float* ego_ptr(unsigned c,
                                                       const float* __restrict__ ue,
                                                       const float* __restrict__ ie) {
    return (c < USER_COUNT) ? ue + (size_t)c * EMB
                            : ie + (size_t)(c - USER_COUNT) * EMB;
}

// acc += w * (4 bf16 values packed in uint2)
static __device__ __forceinline__ void fma4(float4& a, float w, uint2 p) {
    a.x += w * __uint_as_float(p.x << 16);
    a.y += w * __uint_as_float(p.x & 0xFFFF0000u);
    a.z += w * __uint_as_float(p.y << 16);
    a.w += w * __uint_as_float(p.y & 0xFFFF0000u);
}

// ---------------------------------------------------------------------------
// 16-lane-group SpMM row body: lane owns dims [4l, 4l+4) via ONE uint2 (8B)
// gather per edge — half the VMEM instructions of the 32-lane/dword version.
// Unroll 8/4/1; 8 gathers (64 B) in flight per lane.
// ---------------------------------------------------------------------------
static __device__ __forceinline__ float4 spmm_row16(const uint2* __restrict__ edges,
                                                    int s, int e,
                                                    const uint2* __restrict__ x2,
                                                    int l) {
    float4 a0 = {0.f,0.f,0.f,0.f}, a1 = {0.f,0.f,0.f,0.f};
    float4 a2 = {0.f,0.f,0.f,0.f}, a3 = {0.f,0.f,0.f,0.f};
    int i = s;
    for (; i + 7 < e; i += 8) {
        uint2 e0 = edges[i],     e1 = edges[i + 1];
        uint2 e2 = edges[i + 2], e3 = edges[i + 3];
        uint2 e4 = edges[i + 4], e5 = edges[i + 5];
        uint2 e6 = edges[i + 6], e7 = edges[i + 7];
        uint2 p0 = x2[(size_t)(e0.x & COLMASK) * 16 + l];
        uint2 p1 = x2[(size_t)(e1.x & COLMASK) * 16 + l];
        uint2 p2 = x2[(size_t)(e2.x & COLMASK) * 16 + l];
        uint2 p3 = x2[(size_t)(e3.x & COLMASK) * 16 + l];
        uint2 p4 = x2[(size_t)(e4.x & COLMASK) * 16 + l];
        uint2 p5 = x2[(size_t)(e5.x & COLMASK) * 16 + l];
        uint2 p6 = x2[(size_t)(e6.x & COLMASK) * 16 + l];
        uint2 p7 = x2[(size_t)(e7.x & COLMASK) * 16 + l];
        fma4(a0, __uint_as_float(e0.y), p0);
        fma4(a1, __uint_as_float(e1.y), p1);
        fma4(a2, __uint_as_float(e2.y), p2);
        fma4(a3, __uint_as_float(e3.y), p3);
        fma4(a0, __uint_as_float(e4.y), p4);
        fma4(a1, __uint_as_float(e5.y), p5);
        fma4(a2, __uint_as_float(e6.y), p6);
        fma4(a3, __uint_as_float(e7.y), p7);
    }
    if (i + 3 < e) {
        uint2 e0 = edges[i],     e1 = edges[i + 1];
        uint2 e2 = edges[i + 2], e3 = edges[i + 3];
        uint2 p0 = x2[(size_t)(e0.x & COLMASK) * 16 + l];
        uint2 p1 = x2[(size_t)(e1.x & COLMASK) * 16 + l];
        uint2 p2 = x2[(size_t)(e2.x & COLMASK) * 16 + l];
        uint2 p3 = x2[(size_t)(e3.x & COLMASK) * 16 + l];
        fma4(a0, __uint_as_float(e0.y), p0);
        fma4(a1, __uint_as_float(e1.y), p1);
        fma4(a2, __uint_as_float(e2.y), p2);
        fma4(a3, __uint_as_float(e3.y), p3);
        i += 4;
    }
    for (; i < e; ++i) {
        uint2 e0 = edges[i];
        uint2 p0 = x2[(size_t)(e0.x & COLMASK) * 16 + l];
        fma4(a0, __uint_as_float(e0.y), p0);
    }
    float4 r;
    r.x = (a0.x + a1.x) + (a2.x + a3.x);
    r.y = (a0.y + a1.y) + (a2.y + a3.y);
    r.z = (a0.z + a1.z) + (a2.z + a3.z);
    r.w = (a0.w + a1.w) + (a2.w + a3.w);
    return r;
}

// ---------------------------------------------------------------------------
// Fused prep: blocks [0, CONCAT_BLOCKS) do ego->bf16 concat; blocks
// [CONCAT_BLOCKS, +A1_BLOCKS) do the per-block bucket histogram (no global
// atomics: block bb writes its 293 counts to partT[bb*PSTR+t]).
// ---------------------------------------------------------------------------
__global__ void k_prep(const float* __restrict__ ue, const float* __restrict__ ie,
                       unsigned* __restrict__ x,
                       const int* __restrict__ row, int* __restrict__ partT) {
    __shared__ int h[PSTR];
    int tid = threadIdx.x;
    if (blockIdx.x < CONCAT_BLOCKS) {
        const size_t nu4 = (size_t)USER_COUNT * EMB / 4;
        size_t i = (size_t)blockIdx.x * 256 + tid;
        float4 v = (i < nu4) ? ((const float4*)ue)[i] : ((const float4*)ie)[i - nu4];
        uint2 p;
        p.x = pack_bf16x2(v.x, v.y);
        p.y = pack_bf16x2(v.z, v.w);
        ((uint2*)x)[i] = p;
    } else {
        int bb = blockIdx.x - CONCAT_BLOCKS;
        h[tid] = 0;
        if (tid + 256 < PSTR) h[tid + 256] = 0;
        __syncthreads();
        int base = bb * A1_TILE;
        #pragma unroll
        for (int j = 0; j < 8; ++j) {
            int e = base + j * 256 + tid;
            if (e < N_EDGES) atomicAdd(&h[row[e] >> 9], 1);
        }
        __syncthreads();
        if (tid < NBKT) partT[bb * PSTR + tid] = h[tid];
        if (tid + 256 < NBKT) partT[bb * PSTR + tid + 256] = h[tid + 256];
    }
}

// ---------------------------------------------------------------------------
// Parallel column scan: block t exclusive-scans partT[:,t] (611 entries)
// in place and writes the column total to gtot[t].
// ---------------------------------------------------------------------------
__global__ void k_scanbkt(int* __restrict__ partT, int* __restrict__ gtot) {
    __shared__ int sA[256], sB[256];
    int t   = blockIdx.x;
    int tid = threadIdx.x;
    int v0 = 0, v1 = 0, v2 = 0;
    int b0 = tid * 3;
    if (b0 + 0 < A1_BLOCKS) v0 = partT[(b0 + 0) * PSTR + t];
    if (b0 + 1 < A1_BLOCKS) v1 = partT[(b0 + 1) * PSTR + t];
    if (b0 + 2 < A1_BLOCKS) v2 = partT[(b0 + 2) * PSTR + t];
    int s = v0 + v1 + v2;
    sA[tid] = s;
    __syncthreads();
    int* in = sA; int* out = sB;
    for (int off = 1; off < 256; off <<= 1) {
        out[tid] = in[tid] + ((tid >= off) ? in[tid - off] : 0);
        __syncthreads();
        int* tmp = in; in = out; out = tmp;
    }
    int run = in[tid] - s;
    if (b0 + 0 < A1_BLOCKS) { partT[(b0 + 0) * PSTR + t] = run; run += v0; }
    if (b0 + 1 < A1_BLOCKS) { partT[(b0 + 1) * PSTR + t] = run; run += v1; }
    if (b0 + 2 < A1_BLOCKS) { partT[(b0 + 2) * PSTR + t] = run; }
    if (tid == 255) gtot[t] = in[255];
}

// ---------------------------------------------------------------------------
// Cross-bucket scan: gtot[293] -> gstart (exclusive + sentinel), zero ncount.
// ---------------------------------------------------------------------------
__global__ void k_scan2(const int* __restrict__ gtot,
                        int* __restrict__ gstart, int* __restrict__ ncount) {
    __shared__ int sA[512], sB[512];
    int tid = threadIdx.x;
    int va = (tid < NBKT) ? gtot[tid] : 0;
    int vb = (tid + 256 < NBKT) ? gtot[tid + 256] : 0;
    sA[tid] = va; sA[tid + 256] = vb;
    __syncthreads();
    int* in = sA; int* out = sB;
    for (int off = 1; off < 512; off <<= 1) {
        out[tid] = in[tid] + ((tid >= off) ? in[tid - off] : 0);
        int i2 = tid + 256;
        out[i2] = in[i2] + ((i2 >= off) ? in[i2 - off] : 0);
        __syncthreads();
        int* t = in; in = out; out = t;
    }
    if (tid <= NBKT)       gstart[tid] = in[tid] - va;
    if (tid + 256 <= NBKT) gstart[tid + 256] = in[tid + 256] - vb;
    if (tid == 255) ncount[0] = 0;
}

// ---------------------------------------------------------------------------
// Pass A1: bucket-sort edges into edges_a with coherent (staged) writes.
// Per-(block,bucket) base = gstart[t] + scanned partT[bb][t] — no atomics.
// Record: {col | (row&511)<<18, w_f32}
// ---------------------------------------------------------------------------
__global__ void k_binfill(const int* __restrict__ row, const int* __restrict__ col,
                          const float* __restrict__ w,
                          const int* __restrict__ partT,
                          const int* __restrict__ gstart,
                          uint2* __restrict__ edges_a) {
    __shared__ int cnt[512], cnt2[PSTR], gpos[PSTR], sc[PSTR];
    __shared__ int sA[512], sB[512];
    __shared__ uint2 srec[A1_TILE];
    __shared__ int  sdst[A1_TILE];
    int tid = threadIdx.x;
    cnt[tid] = 0; cnt[tid + 256] = 0;
    cnt2[tid] = 0;
    if (tid + 256 < PSTR) cnt2[tid + 256] = 0;
    __syncthreads();

    int ebase   = blockIdx.x * A1_TILE;
    int tilecnt = min(A1_TILE, N_EDGES - ebase);

    int r[8], c[8]; float wv[8];
    #pragma unroll
    for (int j = 0; j < 8; ++j) {
        int e = ebase + j * 256 + tid;
        if (e < N_EDGES) {
            r[j] = row[e]; c[j] = col[e]; wv[j] = w[e];
            atomicAdd(&cnt[r[j] >> 9], 1);
        } else {
            r[j] = -1;
        }
    }
    __syncthreads();

    int* in = sA; int* out = sB;
    in[tid] = cnt[tid]; in[tid + 256] = cnt[tid + 256];
    __syncthreads();
    for (int off = 1; off < 512; off <<= 1) {
        out[tid] = in[tid] + ((tid >= off) ? in[tid - off] : 0);
        int i2 = tid + 256;
        out[i2] = in[i2] + ((i2 >= off) ? in[i2 - off] : 0);
        __syncthreads();
        int* t = in; in = out; out = t;
    }
    #pragma unroll
    for (int k = 0; k < 2; ++k) {
        int b = tid + k * 256;
        if (b < NBKT) {
            sc[b]   = in[b] - cnt[b];
            gpos[b] = gstart[b] + partT[blockIdx.x * PSTR + b];
        }
    }
    __syncthreads();

    #pragma unroll
    for (int j = 0; j < 8; ++j) {
        if (r[j] >= 0) {
            int b  = r[j] >> 9;
            int lp = sc[b] + atomicAdd(&cnt2[b], 1);
            srec[lp] = make_uint2((unsigned)c[j] | ((unsigned)(r[j] & 511) << 18),
                                  __float_as_uint(wv[j]));
            sdst[lp] = gpos[b] + (lp - sc[b]);
        }
    }
    __syncthreads();

    #pragma unroll
    for (int j = 0; j < 8; ++j) {
        int i = j * 256 + tid;
        if (i < tilecnt) edges_a[sdst[i]] = srec[i];
    }
}

// ---------------------------------------------------------------------------
// Pass A2: per-bucket exact CSR, ONE global read pass (edges staged in LDS,
// CAP overflow falls back to global re-read). 293 blocks x 512 threads.
// ---------------------------------------------------------------------------
__global__ __launch_bounds__(512) void k_csrfill(const int* __restrict__ gstart,
                                                 const uint2* __restrict__ edges_a,
                                                 uint2* __restrict__ edges_b,
                                                 int* __restrict__ row_start) {
    __shared__ uint2 srec[CSR_CAP];               // 40 KB
    __shared__ int hist[512], cur[512];
    __shared__ int sA[512], sB[512];
    int tid   = threadIdx.x;
    int b     = blockIdx.x;
    int base  = gstart[b];
    int count = gstart[b + 1] - base;

    hist[tid] = 0;
    __syncthreads();
    for (int i = tid; i < count; i += 512) {
        uint2 rec = edges_a[base + i];
        if (i < CSR_CAP) srec[i] = rec;
        atomicAdd(&hist[(rec.x >> 18) & 511], 1);
    }
    __syncthreads();

    int hv = hist[tid];
    int* in = sA; int* out = sB;
    in[tid] = hv;
    __syncthreads();
    for (int off = 1; off < 512; off <<= 1) {
        out[tid] = in[tid] + ((tid >= off) ? in[tid - off] : 0);
        __syncthreads();
        int* t = in; in = out; out = t;
    }
    int excl = in[tid] - hv;
    row_start[b * BROWS + tid] = base + excl;
    cur[tid] = base + excl;
    __syncthreads();

    for (int i = tid; i < count; i += 512) {
        uint2 rec = (i < CSR_CAP) ? srec[i] : edges_a[base + i];
        int rl = (rec.x >> 18) & 511;
        int pos = atomicAdd(&cur[rl], 1);
        edges_b[pos] = rec;
    }
}

// ---------------------------------------------------------------------------
// Mark+append (dedup'd): bit-array atomicOr; first setter appends to nlist.
// (Compiler wave-aggregates the single-counter atomicAdd — m20.)
// ---------------------------------------------------------------------------
static __device__ __forceinline__ void bit_append(int n, unsigned* __restrict__ bits,
                                                  int* __restrict__ list,
                                                  int* __restrict__ count) {
    unsigned bit = 1u << (n & 31);
    unsigned old = atomicOr(&bits[n >> 5], bit);
    if (!(old & bit)) {
        int pos = atomicAdd(count, 1);
        list[pos] = n;
    }
}

__global__ void k_mark(const int* __restrict__ users, const int* __restrict__ items,
                       const int* __restrict__ row_start,
                       const uint2* __restrict__ edges_b,
                       unsigned* __restrict__ bits,
                       int* __restrict__ nlist, int* __restrict__ ncount) {
    int t = blockIdx.x * blockDim.x + threadIdx.x;
    int g = t >> 3;
    int l = t & 7;
    if (g >= 2 * BATCH) return;
    int node = (g < BATCH) ? users[g] : USER_COUNT + items[g - BATCH];
    if (l == 0) bit_append(node, bits, nlist, ncount);
    int s = row_start[node], e = row_start[node + 1];
    for (int i = s + l; i < e; i += 8)
        bit_append((int)(edges_b[i].x & COLMASK), bits, nlist, ncount);
}

// ---------------------------------------------------------------------------
// Full gather SpMM over bf16 table: 16-lane group per node, 8B gathers.
// ---------------------------------------------------------------------------
__global__ void k_spmm_bf16(const int* __restrict__ row_start,
                            const uint2* __restrict__ edges,
                            const uint2* __restrict__ xin2,
                            uint2* __restrict__ xout2) {
    int g = blockIdx.x * 16 + (threadIdx.x >> 4);
    int l = threadIdx.x & 15;
    if (g >= N_NODES) return;
    float4 a = spmm_row16(edges, row_start[g], row_start[g + 1], xin2, l);
    xout2[(size_t)g * 16 + l] = make_uint2(pack_bf16x2(a.x, a.y),
                                           pack_bf16x2(a.z, a.w));
}

// ---------------------------------------------------------------------------
// List-driven gather SpMM (layer 2 prune): only listed (unique) rows
// ---------------------------------------------------------------------------
__global__ void k_spmm_list(const int* __restrict__ row_start,
                            const uint2* __restrict__ edges,
                            const uint2* __restrict__ xin2,
                            uint2* __restrict__ xout2,
                            const int* __restrict__ list,
                            const int* __restrict__ count) {
    int gi = blockIdx.x * 16 + (threadIdx.x >> 4);
    if (gi >= *count) return;
    int g = list[gi];
    int l = threadIdx.x & 15;
    float4 a = spmm_row16(edges, row_start[g], row_start[g + 1], xin2, l);
    xout2[(size_t)g * 16 + l] = make_uint2(pack_bf16x2(a.x, a.y),
                                           pack_bf16x2(a.z, a.w));
}

// ---------------------------------------------------------------------------
// Fused epilogue: out[g] = 0.25*(ego + x1 + x2 + layer3(x2)), full write.
// 16-lane group per selected slot; 16B ego read and 16B out write per lane.
// ---------------------------------------------------------------------------
__global__ void k_epilogue(const int* __restrict__ users,
                           const int* __restrict__ items,
                           const float* __restrict__ ue,
                           const float* __restrict__ ie,
                           const uint2* __restrict__ x1,
                           const uint2* __restrict__ x2,
                           const int* __restrict__ row_start,
                           const uint2* __restrict__ edges,
                           float* __restrict__ out) {
    int g = blockIdx.x * 16 + (threadIdx.x >> 4);
    int l = threadIdx.x & 15;
    if (g >= 2 * BATCH) return;
    int node = (g < BATCH) ? users[g] : USER_COUNT + items[g - BATCH];
    float4 l3 = spmm_row16(edges, row_start[node], row_start[node + 1], x2, l);
    float4 e = ((const float4*)ego_ptr((unsigned)node, ue, ie))[l];
    uint2 pa = x1[(size_t)node * 16 + l];
    uint2 pb = x2[(size_t)node * 16 + l];
    float4 r;
    r.x = 0.25f * (e.x + __uint_as_float(pa.x << 16)
                       + __uint_as_float(pb.x << 16)        + l3.x);
    r.y = 0.25f * (e.y + __uint_as_float(pa.x & 0xFFFF0000u)
                       + __uint_as_float(pb.x & 0xFFFF0000u) + l3.y);
    r.z = 0.25f * (e.z + __uint_as_float(pa.y << 16)
                       + __uint_as_float(pb.y << 16)        + l3.z);
    r.w = 0.25f * (e.w + __uint_as_float(pa.y & 0xFFFF0000u)
                       + __uint_as_float(pb.y & 0xFFFF0000u) + l3.w);
    ((float4*)out)[(size_t)g * 16 + l] = r;
}

extern "C" void kernel_launch(void* const* d_in, const int* in_sizes, int n_in,
                              void* d_out, int out_size, void* d_ws, size_t ws_size,
                              hipStream_t stream) {
    const float* user_emb    = (const float*)d_in[0];
    const float* item_emb    = (const float*)d_in[1];
    const int*   edge_row    = (const int*)d_in[2];
    const int*   edge_col    = (const int*)d_in[3];
    const float* edge_weight = (const float*)d_in[4];
    const int*   users       = (const int*)d_in[5];
    const int*   items       = (const int*)d_in[6];
    float* out = (float*)d_out;

    // ws layout (~80 MB)
    const size_t node_u32 = (size_t)N_NODES * 32;     // 19.2 MB per bf16 table
    unsigned* xa        = (unsigned*)d_ws;            // ego (bf16)
    unsigned* xb        = xa + node_u32;              // x1
    unsigned* xc        = xb + node_u32;              // x2 (pruned rows only)
    int*      row_start = (int*)(xc + node_u32);      // ROW_ALLOC ints
    int*      gstart    = row_start + ROW_ALLOC;      // 512
    int*      gtot      = gstart + 512;               // 512
    int*      partT     = gtot + 512;                 // A1_BLOCKS*PSTR
    unsigned* bits      = (unsigned*)(partT + A1_BLOCKS * PSTR);  // BITWORDS
    int*      ncount    = (int*)(bits + BITWORDS);    // 16
    int*      nlist     = ncount + 16;                // NLIST_PAD
    uint2*    edges_a   = (uint2*)(nlist + NLIST_PAD);   // 10 MB
    uint2*    edges_b   = edges_a + N_EDGES;             // 10 MB

    // single small memset: dedup bit-array + ncount (contiguous)
    hipMemsetAsync(bits, 0, (BITWORDS + 16) * sizeof(int), stream);

    // prep: concat->bf16 + per-block histogram (fused, no global atomics)
    k_prep<<<CONCAT_BLOCKS + A1_BLOCKS, 256, 0, stream>>>(user_emb, item_emb,
                                                          xa, edge_row, partT);

    // CSR build (atomic-free scans)
    k_scanbkt<<<NBKT, 256, 0, stream>>>(partT, gtot);
    k_scan2<<<1, 256, 0, stream>>>(gtot, gstart, ncount);
    k_binfill<<<A1_BLOCKS, 256, 0, stream>>>(edge_row, edge_col, edge_weight,
                                             partT, gstart, edges_a);
    k_csrfill<<<NBKT, 512, 0, stream>>>(gstart, edges_a, edges_b, row_start);

    // mark+append (dedup'd x2-needed rows)
    k_mark<<<(2 * BATCH * 8 + 255) / 256, 256, 0, stream>>>(users, items, row_start,
                                                            edges_b, bits,
                                                            nlist, ncount);

    // layers (16 nodes per 256-thread block)
    k_spmm_bf16<<<(N_NODES + 15) / 16, 256, 0, stream>>>(row_start, edges_b,
                                                         (const uint2*)xa,
                                                         (uint2*)xb);
    k_spmm_list<<<(N_NODES + 15) / 16, 256, 0, stream>>>(row_start, edges_b,
                                                         (const uint2*)xb,
                                                         (uint2*)xc,
                                                         nlist, ncount);

    // fused epilogue
    k_epilogue<<<(2 * BATCH + 15) / 16, 256, 0, stream>>>(users, items,
                                                          user_emb, item_emb,
                                                          (const uint2*)xb,
                                                          (const uint2*)xc,
                                                          row_start, edges_b,
                                                          out);
}